// Round 7
// baseline (153.460 us; speedup 1.0000x reference)
//
#include <hip/hip_runtime.h>

#define N_NODES 50000
#define N_EDGES 800000
#define F 64
#define NTILES (N_NODES / 16)                  // 3125
#define ATILES ((N_NODES + 31) / 32)           // 1563 blocks (32 nodes each)

#define BNODES 128                             // nodes per bucket
#define NB ((N_NODES + BNODES - 1) / BNODES)   // 391 buckets
#define BCAP 2816                              // bucket capacity (mean 2048 + 4-align pad <=384 + slack)
#define EPB 2048                               // edges per scatter chunk (4/thread @512)
#define SCHUNKS ((N_EDGES + EPB - 1) / EPB)    // 391 (last chunk 1280)
#define SGRID 512                              // scatter_prep grid
#define SBLOCK 512
#define PREP_ELEMS (4 * F * F + N_NODES * 16)  // W entries + float4 groups

typedef __attribute__((ext_vector_type(8))) short short8;   // 8 bf16 (4 VGPRs)
typedef __attribute__((ext_vector_type(4))) float f32x4;    // MFMA accumulator

union frag16 { uint4 u; short8 s; };

// ---------------- bf16 helpers (storage-only; all math fp32/MFMA) ----------------

__device__ __forceinline__ float bflo(unsigned int u) {
    union { unsigned int i; float f; } c; c.i = u << 16; return c.f;
}
__device__ __forceinline__ float bfhi(unsigned int u) {
    union { unsigned int i; float f; } c; c.i = u & 0xFFFF0000u; return c.f;
}
__device__ __forceinline__ unsigned short f2bf(float f) {   // round-nearest-even
    union { float f; unsigned int i; } c; c.f = f;
    unsigned int r = c.i + 0x7FFF + ((c.i >> 16) & 1);
    return (unsigned short)(r >> 16);
}

__device__ __forceinline__ void acc8(float* a, uint4 v) {
    a[0] += bflo(v.x); a[1] += bfhi(v.x);
    a[2] += bflo(v.y); a[3] += bfhi(v.y);
    a[4] += bflo(v.z); a[5] += bfhi(v.z);
    a[6] += bflo(v.w); a[7] += bfhi(v.w);
}

// intra-wave inclusive scan (6 shfl steps, no barriers)
__device__ __forceinline__ int wave_iscan(int s, int lane) {
    #pragma unroll
    for (int off = 1; off < 64; off <<= 1) {
        int t = __shfl_up(s, off);
        if (lane >= off) s += t;
    }
    return s;
}

// ============================ scatter + prep ============================
// all blocks: W fp32[k][n]->bf16 W^T[n][k] (4 mats) + x fp32->bf16 (grid-stride)
// blocks < SCHUNKS: stage EPB edges (src/dst register-cached: ONE global read),
// group by bucket in LDS, reserve global ranges, write grouped.
// Scan over bucket counts is wave-shfl based: 2 barriers total.
// packed edge: src (bits 0-15) | dst_local (bits 16-22) | bucket (bits 23-31)

__global__ __launch_bounds__(SBLOCK) void scatter_prep(
        const int* __restrict__ src, const int* __restrict__ dst,
        int* __restrict__ bcur, unsigned int* __restrict__ binned,
        const float* __restrict__ W0, const float* __restrict__ W1,
        const float* __restrict__ W2, const float* __restrict__ W3,
        unsigned short* __restrict__ Wt,
        const float4* __restrict__ xin, ushort4* __restrict__ xout) {
    __shared__ int lcnt[NB];
    __shared__ int gbase[NB];
    __shared__ int lcur[NB];
    __shared__ int wtot[8];
    __shared__ unsigned int staged[EPB];

    int tid = threadIdx.x;
    int blk = blockIdx.x;

    // ---- prep slice (independent of scatter) ----
    for (int idx = blk * SBLOCK + tid; idx < PREP_ELEMS; idx += SGRID * SBLOCK) {
        if (idx < 4 * F * F) {
            int m = idx >> 12;
            int e = idx & 4095;
            int n = e >> 6, k = e & 63;
            const float* W = (m == 0) ? W0 : (m == 1) ? W1 : (m == 2) ? W2 : W3;
            Wt[m * F * F + n * F + k] = f2bf(W[k * F + n]);
        } else {
            int i = idx - 4 * F * F;
            float4 v = xin[i];
            ushort4 o;
            o.x = f2bf(v.x); o.y = f2bf(v.y); o.z = f2bf(v.z); o.w = f2bf(v.w);
            xout[i] = o;
        }
    }

    if (blk >= SCHUNKS) return;                // block-uniform: whole block skips

    int lane = tid & 63;
    int wid  = tid >> 6;

    int e0 = blk * EPB;
    int e1 = min(N_EDGES, e0 + EPB);
    for (int i = tid; i < NB; i += SBLOCK) lcnt[i] = 0;
    __syncthreads();

    // register-cache the edges: one global read instead of two
    int dreg[4], sreg[4];
    #pragma unroll
    for (int t = 0; t < 4; ++t) {
        int i = e0 + tid + t * SBLOCK;
        if (i < e1) { dreg[t] = dst[i]; sreg[t] = src[i]; }
        else        { dreg[t] = -1;     sreg[t] = 0; }
    }
    #pragma unroll
    for (int t = 0; t < 4; ++t)
        if (dreg[t] >= 0) atomicAdd(&lcnt[dreg[t] >> 7], 1);
    __syncthreads();

    // wave-shfl inclusive scan over lcnt[0..NB) (padded with zeros to 512)
    int v = (tid < NB) ? lcnt[tid] : 0;
    int s = wave_iscan(v, lane);
    if (lane == 63) wtot[wid] = s;
    __syncthreads();
    int woff = 0;
    #pragma unroll
    for (int w = 0; w < 7; ++w)
        if (w < wid) woff += wtot[w];
    if (tid < NB) {
        int incl = s + woff;
        int excl = incl - v;
        int resv = (v > 0) ? atomicAdd(&bcur[tid], v) : 0;
        gbase[tid] = tid * BCAP + resv - excl;
        lcur[tid] = excl;
    }
    __syncthreads();

    #pragma unroll
    for (int t = 0; t < 4; ++t) {
        if (dreg[t] >= 0) {
            int d = dreg[t];
            int b = d >> 7;
            int dl = d & 127;
            int posl = atomicAdd(&lcur[b], 1);
            staged[posl] = (unsigned)sreg[t] | ((unsigned)dl << 16) | ((unsigned)b << 23);
        }
    }
    __syncthreads();

    int cnt = e1 - e0;
    for (int i = tid; i < cnt; i += SBLOCK) {
        unsigned pk = staged[i];
        binned[gbase[pk >> 23] + i] = pk;      // grouped -> mostly coalesced
    }
}

// ============================ bucket CSR build ============================
// per bucket: node counts + wave-shfl scan -> row_beg/degs/csr16 (binned reg-cached)
// Each node's csr row is padded to a multiple of 4 entries (pad slots = index 0)
// so row_beg is 4-aligned: the gather loop loads indices as one ushort4 per quad.

__global__ __launch_bounds__(512) void bucket_build(
        const unsigned int* __restrict__ binned, const int* __restrict__ bcur,
        int* __restrict__ row_beg, unsigned short* __restrict__ degs,
        unsigned short* __restrict__ csr16) {
    __shared__ int ncnt[BNODES];
    __shared__ int ncur[BNODES];
    __shared__ int w0tot;
    int blk = blockIdx.x;
    int tid = threadIdx.x;
    int lane = tid & 63;
    int wid  = tid >> 6;
    int start = blk * BCAP;
    int cnt = min(bcur[blk], BCAP);

    for (int i = tid; i < BNODES; i += 512) ncnt[i] = 0;
    __syncthreads();

    // register-cache bucket entries: one global read instead of two
    unsigned preg[6];
    #pragma unroll
    for (int t = 0; t < 6; ++t) {
        int i = tid + t * 512;
        preg[t] = (i < cnt) ? binned[start + i] : 0xFFFFFFFFu;
    }
    #pragma unroll
    for (int t = 0; t < 6; ++t)
        if (preg[t] != 0xFFFFFFFFu)
            atomicAdd(&ncnt[(preg[t] >> 16) & 127], 1);
    __syncthreads();

    // wave-shfl inclusive scan over 4-rounded counts (waves 0,1 carry the data)
    int v  = (tid < BNODES) ? ncnt[tid] : 0;
    int vp = (v + 3) & ~3;                     // padded row size (4-aligned)
    int s = wave_iscan(vp, lane);
    if (tid == 63) w0tot = s;
    __syncthreads();
    if (wid == 1) s += w0tot;
    if (tid < BNODES) {
        int excl = s - vp;                     // 4-aligned (all vp are multiples of 4)
        ncur[tid] = excl;
        int node = blk * BNODES + tid;
        row_beg[node] = start + excl;
        degs[node] = (unsigned short)v;
        for (int k = v; k < vp; ++k)           // init pad slots -> valid index 0
            csr16[start + excl + k] = 0;
    }
    __syncthreads();

    #pragma unroll
    for (int t = 0; t < 6; ++t) {
        if (preg[t] != 0xFFFFFFFFu) {
            unsigned pk = preg[t];
            int dl = (pk >> 16) & 127;
            int pos = start + atomicAdd(&ncur[dl], 1);
            csr16[pos] = (unsigned short)(pk & 0xFFFF);
        }
    }
}

// ============ fused aggregate + MFMA transform: one block per 32-node tile ============
// Aggregation: 8 lanes/node x 8 nodes/wave, no cross-lane reduce. Rows are
// 4-aligned+padded: indices load as ONE ushort4 per quad (was 4 scalar loads
// + 4 clamps), next quad's indices prefetched before the current gathers.
// Pad gathers hit row 0 (L1-hot) and are predicated out of the accumulate.
// lagg XOR-swizzled (16-way -> 2-way LDS bank conflict on the transform read).
// Then barrier; waves 0,1 each run the MFMA transform for one 16-node tile.
// PROJ=true fuses the layer-3 projection into p (neigh) / q (self).

template <bool PROJ>
__global__ __launch_bounds__(256, 6) void aggtf_kernel(
        const uint4* __restrict__ xh8, const int* __restrict__ row_beg,
        const unsigned short* __restrict__ degs,
        const unsigned short* __restrict__ csr16,
        const uint4* __restrict__ Wst, const uint4* __restrict__ Wnt,
        const float* __restrict__ b, unsigned short* __restrict__ out_bf,
        const float* __restrict__ Ws3, const float* __restrict__ Wn3,
        float* __restrict__ pout, float* __restrict__ qout) {
    __shared__ uint4 lagg[32 * 8];             // 32 nodes x 64 feats bf16 (4 KB)
    int tid  = threadIdx.x;
    int wave = tid >> 6;
    int lane = tid & 63;
    int base = blockIdx.x * 32;

    int nsub = lane >> 3;                      // node within wave's 8
    int sub  = lane & 7;                       // ushort8 feature slice
    int node_l = wave * 8 + nsub;              // 0..31 within block

    // batched row metadata: lanes 0..31 load all 32 nodes, broadcast by shfl
    int rb_l = 0, dg_l = 0;
    if (lane < 32 && base + lane < N_NODES) {
        rb_l = row_beg[base + lane];
        dg_l = degs[base + lane];
    }
    int beg = __shfl(rb_l, node_l);            // 4-aligned
    int deg = __shfl(dg_l, node_l);

    float a0[8], a1[8];
    #pragma unroll
    for (int j = 0; j < 8; ++j) { a0[j] = 0.f; a1[j] = 0.f; }

    const ushort4* crow = (const ushort4*)(csr16 + beg);
    int nq = (deg + 3) >> 2;                   // quads (last may contain pad)
    ushort4 cq;
    if (nq > 0) cq = crow[0];
    int q = 0;
    for (; q + 1 < nq; ++q) {                  // steady: prefetch next quad's indices
        ushort4 nqv = crow[q + 1];
        uint4 v0 = xh8[cq.x * 8 + sub];
        uint4 v1 = xh8[cq.y * 8 + sub];
        uint4 v2 = xh8[cq.z * 8 + sub];
        uint4 v3 = xh8[cq.w * 8 + sub];
        acc8(a0, v0); acc8(a1, v1); acc8(a0, v2); acc8(a1, v3);
        cq = nqv;
    }
    if (nq > 0) {                              // last quad: predicated accumulate
        int done = q * 4;
        uint4 v0 = xh8[cq.x * 8 + sub];
        uint4 v1 = xh8[cq.y * 8 + sub];
        uint4 v2 = xh8[cq.z * 8 + sub];
        uint4 v3 = xh8[cq.w * 8 + sub];
        acc8(a0, v0);
        if (done + 1 < deg) acc8(a1, v1);
        if (done + 2 < deg) acc8(a0, v2);
        if (done + 3 < deg) acc8(a1, v3);
    }
    {
        float inv = (deg > 0) ? (1.0f / (float)deg) : 0.f;
        unsigned short o[8];
        #pragma unroll
        for (int j = 0; j < 8; ++j)
            o[j] = f2bf((a0[j] + a1[j]) * inv);
        uint4 pk;
        pk.x = (unsigned)o[0] | ((unsigned)o[1] << 16);
        pk.y = (unsigned)o[2] | ((unsigned)o[3] << 16);
        pk.z = (unsigned)o[4] | ((unsigned)o[5] << 16);
        pk.w = (unsigned)o[6] | ((unsigned)o[7] << 16);
        lagg[node_l * 8 + (sub ^ (node_l & 7))] = pk;   // XOR-swizzled slice
    }
    __syncthreads();

    if (wave >= 2) return;                     // 2 waves transform 2 tiles
    int tbase = base + wave * 16;
    if (tbase + 16 > N_NODES) return;          // N_NODES % 16 == 0: all-or-nothing

    int lo = lane & 15, hi = lane >> 4;

    float bias_s[4];
    #pragma unroll
    for (int jt = 0; jt < 4; ++jt) bias_s[jt] = b[jt * 16 + lo];
    float w3n_s[4], w3s_s[4];
    if constexpr (PROJ) {
        #pragma unroll
        for (int jt = 0; jt < 4; ++jt) {
            w3n_s[jt] = Wn3[jt * 16 + lo];
            w3s_s[jt] = Ws3[jt * 16 + lo];
        }
    }

    frag16 ax[2], aa[2];
    #pragma unroll
    for (int kt = 0; kt < 2; ++kt) {
        int row = wave * 16 + lo;
        ax[kt].u = xh8[(tbase + lo) * 8 + kt * 4 + hi];
        aa[kt].u = lagg[row * 8 + ((kt * 4 + hi) ^ (row & 7))];   // matching swizzle
    }

    f32x4 acc[4];
    #pragma unroll
    for (int jt = 0; jt < 4; ++jt)
        acc[jt] = f32x4{bias_s[jt], bias_s[jt], bias_s[jt], bias_s[jt]};

    // per-jt W loading: only 4 fragments live at a time (VGPR budget),
    // same per-acc MFMA order as before -> bit-identical
    #pragma unroll
    for (int jt = 0; jt < 4; ++jt) {
        int n = jt * 16 + lo;
        frag16 ws0, wn0, ws1, wn1;
        ws0.u = Wst[n * 8 + 0 + hi];
        wn0.u = Wnt[n * 8 + 0 + hi];
        ws1.u = Wst[n * 8 + 4 + hi];
        wn1.u = Wnt[n * 8 + 4 + hi];
        acc[jt] = __builtin_amdgcn_mfma_f32_16x16x32_bf16(ax[0].s, ws0.s, acc[jt], 0, 0, 0);
        acc[jt] = __builtin_amdgcn_mfma_f32_16x16x32_bf16(aa[0].s, wn0.s, acc[jt], 0, 0, 0);
        acc[jt] = __builtin_amdgcn_mfma_f32_16x16x32_bf16(ax[1].s, ws1.s, acc[jt], 0, 0, 0);
        acc[jt] = __builtin_amdgcn_mfma_f32_16x16x32_bf16(aa[1].s, wn1.s, acc[jt], 0, 0, 0);
    }

    if constexpr (!PROJ) {
        #pragma unroll
        for (int jt = 0; jt < 4; ++jt)
            #pragma unroll
            for (int r = 0; r < 4; ++r) {
                float h = fmaxf(acc[jt][r], 0.f);
                out_bf[(tbase + hi * 4 + r) * F + jt * 16 + lo] = f2bf(h);
            }
    } else {
        #pragma unroll
        for (int r = 0; r < 4; ++r) {
            float pr = 0.f, qr = 0.f;
            #pragma unroll
            for (int jt = 0; jt < 4; ++jt) {
                float h = fmaxf(acc[jt][r], 0.f);
                pr += h * w3n_s[jt];
                qr += h * w3s_s[jt];
            }
            #pragma unroll
            for (int off = 1; off < 16; off <<= 1) {
                pr += __shfl_xor(pr, off);
                qr += __shfl_xor(qr, off);
            }
            if (lo == 0) {
                pout[tbase + hi * 4 + r] = pr;
                qout[tbase + hi * 4 + r] = qr;
            }
        }
    }
}

// ================ final: out = q + mean_agg(p) + b3, 16 lanes per node ================

__global__ __launch_bounds__(256) void final_kernel(
        const int* __restrict__ row_beg, const unsigned short* __restrict__ degs,
        const unsigned short* __restrict__ csr16,
        const float* __restrict__ p, const float* __restrict__ q,
        const float* __restrict__ b3, float* __restrict__ out, int n_nodes) {
    int grp = threadIdx.x >> 4;
    int ln  = threadIdx.x & 15;
    int node = blockIdx.x * 16 + grp;
    if (node >= n_nodes) return;
    int beg = row_beg[node];
    int deg = degs[node];
    int end = beg + deg;
    float s = 0.f;
    for (int i = beg + ln; i < end; i += 16) s += p[csr16[i]];
    #pragma unroll
    for (int off = 1; off < 16; off <<= 1) s += __shfl_xor(s, off);
    if (ln == 0) {
        float inv = (deg > 0) ? (1.0f / (float)deg) : 0.f;
        out[node] = q[node] + s * inv + b3[0];
    }
}

// ---------------- launch ----------------

extern "C" void kernel_launch(void* const* d_in, const int* in_sizes, int n_in,
                              void* d_out, int out_size, void* d_ws, size_t ws_size,
                              hipStream_t stream) {
    const float* x   = (const float*)d_in[0];
    const int*   src = (const int*)d_in[1];
    const int*   dst = (const int*)d_in[2];
    const float* Ws1 = (const float*)d_in[3];
    const float* Wn1 = (const float*)d_in[4];
    const float* b1  = (const float*)d_in[5];
    const float* Ws2 = (const float*)d_in[6];
    const float* Wn2 = (const float*)d_in[7];
    const float* b2  = (const float*)d_in[8];
    const float* Ws3 = (const float*)d_in[9];
    const float* Wn3 = (const float*)d_in[10];
    const float* b3  = (const float*)d_in[11];
    float* out = (float*)d_out;

    char* ws = (char*)d_ws;
    size_t cur = 0;
    auto alloc = [&](size_t bytes) -> void* {
        void* ptr = ws + cur;
        cur += (bytes + 255) & ~(size_t)255;
        return ptr;
    };

    int*            bcur     = (int*)  alloc(NB * sizeof(int));
    unsigned int*   binned   = (unsigned int*)alloc((size_t)NB * BCAP * sizeof(unsigned int));
    int*            row_beg  = (int*)  alloc((size_t)(NB * BNODES) * sizeof(int));
    unsigned short* degs     = (unsigned short*)alloc((size_t)(NB * BNODES) * sizeof(unsigned short));
    unsigned short* csr16    = (unsigned short*)alloc((size_t)NB * BCAP * sizeof(unsigned short));
    unsigned short* xh       = (unsigned short*)alloc((size_t)N_NODES * F * 2);  // bf16 x
    unsigned short* h1h      = (unsigned short*)alloc((size_t)N_NODES * F * 2);  // bf16 h1
    unsigned short* Wt       = (unsigned short*)alloc(4 * F * F * 2);            // bf16 W^T x4
    float*          p        = (float*)alloc(N_NODES * sizeof(float));
    float*          q        = (float*)alloc(N_NODES * sizeof(float));

    unsigned short* Wst1 = Wt;
    unsigned short* Wnt1 = Wt + F * F;
    unsigned short* Wst2 = Wt + 2 * F * F;
    unsigned short* Wnt2 = Wt + 3 * F * F;

    (void)hipMemsetAsync(bcur, 0, NB * sizeof(int), stream);
    scatter_prep<<<SGRID, SBLOCK, 0, stream>>>(
        src, dst, bcur, binned, Ws1, Wn1, Ws2, Wn2, Wt, (const float4*)x, (ushort4*)xh);
    bucket_build<<<NB, 512, 0, stream>>>(binned, bcur, row_beg, degs, csr16);

    // layer 1: fused aggregate + transform
    aggtf_kernel<false><<<ATILES, 256, 0, stream>>>(
        (const uint4*)xh, row_beg, degs, csr16,
        (const uint4*)Wst1, (const uint4*)Wnt1, b1, h1h,
        nullptr, nullptr, nullptr, nullptr);
    // layer 2: fused aggregate + transform + layer-3 projection
    aggtf_kernel<true><<<ATILES, 256, 0, stream>>>(
        (const uint4*)h1h, row_beg, degs, csr16,
        (const uint4*)Wst2, (const uint4*)Wnt2, b2, nullptr,
        Ws3, Wn3, p, q);
    // layer 3: aggregate scalars
    final_kernel<<<(N_NODES + 15) / 16, 256, 0, stream>>>(
        row_beg, degs, csr16, p, q, b3, out, N_NODES);
}